// Round 1
// baseline (1151.046 us; speedup 1.0000x reference)
//
#include <hip/hip_runtime.h>
#include <hip/hip_bf16.h>

#define B_  64
#define M_  1024
#define D_  1024
#define H_  8
#define HD_ 128
#define BM_ (B_*M_)

#define CELU_A  1.3f
#define CELU_IA 0.7692307692307693f
#define GN_EPSF 1e-5f

typedef float floatx4 __attribute__((ext_vector_type(4)));
typedef __bf16 bf16x8 __attribute__((ext_vector_type(8)));

__device__ __forceinline__ void gload_lds16(const void* g, void* l) {
    __builtin_amdgcn_global_load_lds((const __attribute__((address_space(1))) void*)g,
                                     (__attribute__((address_space(3))) void*)l, 16, 0, 0);
}

__device__ __forceinline__ float celu_f(float x) {
    return x > 0.f ? x : (CELU_A * __expf(x * CELU_IA) - CELU_A);
}

// ---------------------------------------------------------------------------
// Transpose + fp32->bf16 convert for the two big weight matrices.
// Wt[n*D + d] = (bf16) W[d*D + n]
// ---------------------------------------------------------------------------
__global__ void transpose_convert(const float* __restrict__ W0, const float* __restrict__ W1m,
                                  __bf16* __restrict__ T0, __bf16* __restrict__ T1) {
    __shared__ float tile[32][33];
    int id = blockIdx.x;
    const float* W = (id < 1024) ? W0 : W1m;
    __bf16* T = (id < 1024) ? T0 : T1;
    id &= 1023;
    int bx = id & 31, by = id >> 5;
    int tx = threadIdx.x & 31, ty = threadIdx.x >> 5;  // 32 x 8
    #pragma unroll
    for (int i = 0; i < 32; i += 8)
        tile[ty + i][tx] = W[(size_t)(by*32 + ty + i) * D_ + bx*32 + tx];
    __syncthreads();
    #pragma unroll
    for (int i = 0; i < 32; i += 8)
        T[(size_t)(bx*32 + ty + i) * D_ + by*32 + tx] = (__bf16)tile[tx][ty + i];
}

// ---------------------------------------------------------------------------
// Small projection (query / value1): out = GN(celu(x@W + b)) * g + beta
// grid = B*H, block = 128 threads (one head's 128 cols per block)
// extras: also compute qn, and qw1 = (q/max(qn,1e-12)) @ W1
// ---------------------------------------------------------------------------
__global__ void proj_small(const float* __restrict__ x, const float* __restrict__ W,
                           const float* __restrict__ bias, const float* __restrict__ g,
                           const float* __restrict__ beta, float* __restrict__ out,
                           float* __restrict__ qn_out, const float* __restrict__ W1,
                           float* __restrict__ qw1, int extras) {
    __shared__ float sX[D_];
    __shared__ float sred[4];
    __shared__ float sQd[HD_];
    const int bh = blockIdx.x;
    const int b = bh >> 3, h = bh & 7;
    const int tid = threadIdx.x;  // 128

    #pragma unroll
    for (int i = 0; i < D_/128; i++) sX[i*128 + tid] = x[(size_t)b*D_ + i*128 + tid];
    __syncthreads();

    const int col = h*HD_ + tid;
    float acc = bias[col];
    const float* Wp = W + col;
    #pragma unroll 16
    for (int d = 0; d < D_; d++) acc = fmaf(sX[d], Wp[(size_t)d*D_], acc);

    float y = celu_f(acc);

    float s1 = y, s2 = y*y;
    #pragma unroll
    for (int off = 1; off < 64; off <<= 1) { s1 += __shfl_xor(s1, off, 64); s2 += __shfl_xor(s2, off, 64); }
    if ((tid & 63) == 0) { sred[tid >> 6] = s1; sred[2 + (tid >> 6)] = s2; }
    __syncthreads();
    s1 = sred[0] + sred[1]; s2 = sred[2] + sred[3];
    float mu = s1 * (1.f/HD_);
    float var = fmaxf(s2 * (1.f/HD_) - mu*mu, 0.f);
    float rstd = rsqrtf(var + GN_EPSF);
    float k = (y - mu) * rstd * g[col] + beta[col];
    out[(size_t)b*D_ + col] = k;

    if (extras) {
        __syncthreads();
        float q2 = k*k;
        #pragma unroll
        for (int off = 1; off < 64; off <<= 1) q2 += __shfl_xor(q2, off, 64);
        if ((tid & 63) == 0) sred[tid >> 6] = q2;
        __syncthreads();
        float qn = sqrtf(sred[0] + sred[1]);
        if (tid == 0) qn_out[bh] = qn;
        sQd[tid] = k / fmaxf(qn, 1e-12f);
        __syncthreads();
        if (tid < 64) {
            float s = 0.f;
            #pragma unroll 16
            for (int d2 = 0; d2 < HD_; d2++) s = fmaf(sQd[d2], W1[d2*64 + tid], s);
            qw1[bh*64 + tid] = s;
        }
    }
}

// ---------------------------------------------------------------------------
// Big GEMM core: C(128x128) tile of A(BMxD) @ Wt^T, bf16 MFMA, BK=32.
// grid = (BM/128)*(D/128) = 4096 ; block = 256 (4 waves, 2x2 of 64x64)
// Tile cols == one head (HD=128), so GN is tile-local.
// ---------------------------------------------------------------------------
#define TM 128
#define BK 32
#define ASTR 40   // padded LDS stride for A tile (elements)

#define GEMM_CORE(Aptr, Btptr)                                                          \
    const int tid = threadIdx.x;                                                        \
    const int h = blockIdx.x & 7;                                                       \
    const int row0 = (blockIdx.x >> 3) * TM;                                            \
    const int b = row0 >> 10;                                                           \
    const int col0 = h * HD_;                                                           \
    const int lane = tid & 63;                                                          \
    const int wv = tid >> 6;                                                            \
    const int wrow = wv >> 1, wcol = wv & 1;                                            \
    const int quad = lane >> 4, l15 = lane & 15;                                        \
    floatx4 acc[4][4];                                                                  \
    {   floatx4 z = {0.f, 0.f, 0.f, 0.f};                                               \
        _Pragma("unroll") for (int i = 0; i < 4; i++)                                   \
        _Pragma("unroll") for (int j = 0; j < 4; j++) acc[i][j] = z;  }                 \
    const int ar = tid >> 1;                                                            \
    const int ak = (tid & 1) << 4;                                                      \
    const float* Ap = Aptr + (size_t)(row0 + ar) * D_ + ak;                             \
    const __bf16* Bp0 = Btptr + (size_t)(col0 + (tid >> 2)) * D_ + ((tid & 3) << 3);    \
    const __bf16* Bp1 = Btptr + (size_t)(col0 + 64 + (tid >> 2)) * D_ + ((tid & 3) << 3);\
    __bf16* Bd0 = Bs + tid * 8;                                                         \
    __bf16* Bd1 = Bs + (tid + 256) * 8;                                                 \
    for (int k0 = 0; k0 < D_; k0 += BK) {                                               \
        __syncthreads();                                                                \
        gload_lds16(Bp0 + k0, Bd0);                                                     \
        gload_lds16(Bp1 + k0, Bd1);                                                     \
        {                                                                               \
            const float* p = Ap + k0;                                                   \
            floatx4 f0 = *(const floatx4*)p;                                            \
            floatx4 f1 = *(const floatx4*)(p + 4);                                      \
            floatx4 f2 = *(const floatx4*)(p + 8);                                      \
            floatx4 f3 = *(const floatx4*)(p + 12);                                     \
            bf16x8 u0, u1;                                                              \
            _Pragma("unroll") for (int i = 0; i < 4; i++) {                             \
                u0[i] = (__bf16)f0[i]; u0[i+4] = (__bf16)f1[i];                         \
                u1[i] = (__bf16)f2[i]; u1[i+4] = (__bf16)f3[i]; }                       \
            *(bf16x8*)(As + ar*ASTR + ak)     = u0;                                     \
            *(bf16x8*)(As + ar*ASTR + ak + 8) = u1;                                     \
        }                                                                               \
        __syncthreads();                                                                \
        bf16x8 fa[4], fb[4];                                                            \
        _Pragma("unroll") for (int i = 0; i < 4; i++)                                   \
            fa[i] = *(const bf16x8*)(As + (wrow*64 + i*16 + l15)*ASTR + quad*8);        \
        _Pragma("unroll") for (int i = 0; i < 4; i++)                                   \
            fb[i] = *(const bf16x8*)(Bs + (wcol*64 + i*16 + l15)*BK + quad*8);          \
        _Pragma("unroll") for (int mi = 0; mi < 4; mi++)                                \
        _Pragma("unroll") for (int ni = 0; ni < 4; ni++)                                \
            acc[mi][ni] = __builtin_amdgcn_mfma_f32_16x16x32_bf16(fa[mi], fb[ni],       \
                                                                  acc[mi][ni], 0, 0, 0);\
    }

// Key path: epilogue computes dot(q, k_row) and ||k_row|| per row.
__global__ __launch_bounds__(256, 2) void gemm_key(
    const float* __restrict__ A, const __bf16* __restrict__ Bt,
    const float* __restrict__ bias, const float* __restrict__ gv,
    const float* __restrict__ betav, const float* __restrict__ qv,
    float* __restrict__ dotv, float* __restrict__ knv) {
    __shared__ __attribute__((aligned(16))) __bf16 As[TM * ASTR];
    __shared__ __attribute__((aligned(16))) __bf16 Bs[TM * BK];
    __shared__ float red0[2][TM], red1[2][TM], redD[2][TM], redK[2][TM];

    GEMM_CORE(A, Bt)

    float biasc[4], gc[4], bc[4], qc[4];
    #pragma unroll
    for (int ni = 0; ni < 4; ni++) {
        int c = col0 + wcol*64 + ni*16 + l15;
        biasc[ni] = bias[c]; gc[ni] = gv[c]; bc[ni] = betav[c];
        qc[ni] = qv[(size_t)b*D_ + c];
    }
    #pragma unroll
    for (int mi = 0; mi < 4; mi++)
    #pragma unroll
    for (int ni = 0; ni < 4; ni++)
    #pragma unroll
    for (int r = 0; r < 4; r++)
        acc[mi][ni][r] = celu_f(acc[mi][ni][r] + biasc[ni]);

    #pragma unroll
    for (int mi = 0; mi < 4; mi++)
    #pragma unroll
    for (int r = 0; r < 4; r++) {
        float s1 = 0.f, s2 = 0.f;
        #pragma unroll
        for (int ni = 0; ni < 4; ni++) { float v = acc[mi][ni][r]; s1 += v; s2 += v*v; }
        #pragma unroll
        for (int off = 1; off < 16; off <<= 1) { s1 += __shfl_xor(s1, off, 16); s2 += __shfl_xor(s2, off, 16); }
        if (l15 == 0) { int rr = wrow*64 + mi*16 + quad*4 + r; red0[wcol][rr] = s1; red1[wcol][rr] = s2; }
    }
    __syncthreads();
    #pragma unroll
    for (int mi = 0; mi < 4; mi++)
    #pragma unroll
    for (int r = 0; r < 4; r++) {
        int rr = wrow*64 + mi*16 + quad*4 + r;
        float s1 = red0[0][rr] + red0[1][rr];
        float s2 = red1[0][rr] + red1[1][rr];
        float mu = s1 * (1.f/HD_);
        float var = fmaxf(s2 * (1.f/HD_) - mu*mu, 0.f);
        float rstd = rsqrtf(var + GN_EPSF);
        float dp = 0.f, kp = 0.f;
        #pragma unroll
        for (int ni = 0; ni < 4; ni++) {
            float kk = (acc[mi][ni][r] - mu) * rstd * gc[ni] + bc[ni];
            dp = fmaf(kk, qc[ni], dp);
            kp = fmaf(kk, kk, kp);
        }
        #pragma unroll
        for (int off = 1; off < 16; off <<= 1) { dp += __shfl_xor(dp, off, 16); kp += __shfl_xor(kp, off, 16); }
        if (l15 == 0) { redD[wcol][rr] = dp; redK[wcol][rr] = kp; }
    }
    __syncthreads();
    if (tid < TM) {
        int gr = row0 + tid;
        size_t oi = ((size_t)(b*H_ + h)) * M_ + (gr & (M_ - 1));
        dotv[oi] = redD[0][tid] + redD[1][tid];
        knv[oi]  = sqrtf(redK[0][tid] + redK[1][tid]);
    }
}

// value2 path: epilogue accumulates v2o[b,h,:] += a_sp[b,h,m] * v2_row
__global__ __launch_bounds__(256, 2) void gemm_v2(
    const float* __restrict__ A, const __bf16* __restrict__ Bt,
    const float* __restrict__ bias, const float* __restrict__ gv,
    const float* __restrict__ betav, const float* __restrict__ asp,
    float* __restrict__ v2o) {
    __shared__ __attribute__((aligned(16))) __bf16 As[TM * ASTR];
    __shared__ __attribute__((aligned(16))) __bf16 Bs[TM * BK];
    __shared__ float red0[2][TM], red1[2][TM];
    __shared__ float sAsp[TM];

    GEMM_CORE(A, Bt)

    if (tid < TM) {
        int gr = row0 + tid;
        sAsp[tid] = asp[((size_t)(b*H_ + h)) * M_ + (gr & (M_ - 1))];
    }
    float biasc[4], gc[4], bc[4];
    #pragma unroll
    for (int ni = 0; ni < 4; ni++) {
        int c = col0 + wcol*64 + ni*16 + l15;
        biasc[ni] = bias[c]; gc[ni] = gv[c]; bc[ni] = betav[c];
    }
    #pragma unroll
    for (int mi = 0; mi < 4; mi++)
    #pragma unroll
    for (int ni = 0; ni < 4; ni++)
    #pragma unroll
    for (int r = 0; r < 4; r++)
        acc[mi][ni][r] = celu_f(acc[mi][ni][r] + biasc[ni]);

    #pragma unroll
    for (int mi = 0; mi < 4; mi++)
    #pragma unroll
    for (int r = 0; r < 4; r++) {
        float s1 = 0.f, s2 = 0.f;
        #pragma unroll
        for (int ni = 0; ni < 4; ni++) { float v = acc[mi][ni][r]; s1 += v; s2 += v*v; }
        #pragma unroll
        for (int off = 1; off < 16; off <<= 1) { s1 += __shfl_xor(s1, off, 16); s2 += __shfl_xor(s2, off, 16); }
        if (l15 == 0) { int rr = wrow*64 + mi*16 + quad*4 + r; red0[wcol][rr] = s1; red1[wcol][rr] = s2; }
    }
    __syncthreads();
    float cs[4] = {0.f, 0.f, 0.f, 0.f};
    #pragma unroll
    for (int mi = 0; mi < 4; mi++)
    #pragma unroll
    for (int r = 0; r < 4; r++) {
        int rr = wrow*64 + mi*16 + quad*4 + r;
        float s1 = red0[0][rr] + red0[1][rr];
        float s2 = red1[0][rr] + red1[1][rr];
        float mu = s1 * (1.f/HD_);
        float var = fmaxf(s2 * (1.f/HD_) - mu*mu, 0.f);
        float rstd = rsqrtf(var + GN_EPSF);
        float w = sAsp[rr];
        #pragma unroll
        for (int ni = 0; ni < 4; ni++) {
            float vv = (acc[mi][ni][r] - mu) * rstd * gc[ni] + bc[ni];
            cs[ni] = fmaf(w, vv, cs[ni]);
        }
    }
    #pragma unroll
    for (int ni = 0; ni < 4; ni++) {
        cs[ni] += __shfl_xor(cs[ni], 16, 64);
        cs[ni] += __shfl_xor(cs[ni], 32, 64);
    }
    if (quad == 0) {
        #pragma unroll
        for (int ni = 0; ni < 4; ni++)
            atomicAdd(&v2o[(size_t)b*D_ + col0 + wcol*64 + ni*16 + l15], cs[ni]);
    }
}

// ---------------------------------------------------------------------------
// Attention weights from small data: a_sp (softmax) and a_ch (sigmoid channel gate)
// grid = B*H, block = 256
// ---------------------------------------------------------------------------
__global__ __launch_bounds__(256) void attn_small(
    const float* __restrict__ dotv, const float* __restrict__ knv,
    const float* __restrict__ qn_in, const float* __restrict__ qw1,
    const float* __restrict__ b1, const float* __restrict__ Wl,
    const float* __restrict__ bl, const float* __restrict__ Wl2,
    const float* __restrict__ bl2, const float* __restrict__ mask,
    float* __restrict__ asp, float* __restrict__ ach) {
    __shared__ float sqw[64], sb1[64], sWl[64];
    __shared__ float sredA[4], sredB[4], sMsum[4];
    __shared__ float sPool[4][64];
    __shared__ float sPoolF[64];
    const int bh = blockIdx.x;
    const int b = bh >> 3;
    const int tid = threadIdx.x, lane = tid & 63, wv = tid >> 6;
    if (tid < 64) { sqw[tid] = qw1[bh*64 + tid]; sb1[tid] = b1[tid]; sWl[tid] = Wl[tid]; }
    __syncthreads();
    const float rqn = 1.f / fmaxf(qn_in[bh], 1e-8f);
    const float blv = bl[0];
    const size_t base = (size_t)bh * M_;
    float pacc[64];
    #pragma unroll
    for (int j = 0; j < 64; j++) pacc[j] = 0.f;
    float lg[4], e[4];
    float msum = 0.f;
    #pragma unroll
    for (int i = 0; i < 4; i++) {
        int m = i*256 + tid;
        float kn = fmaxf(knv[base + m], 1e-8f);
        float cosv = dotv[base + m] * rqn / kn;
        float mk = mask[(size_t)b*M_ + m];
        msum += mk;
        float l = blv;
        #pragma unroll
        for (int j = 0; j < 64; j++) {
            float a = fmaxf(fmaf(cosv, sqw[j], sb1[j]), 0.f);
            l = fmaf(a, sWl[j], l);
            pacc[j] = fmaf(a, mk, pacc[j]);
        }
        lg[i] = (mk == 0.f) ? -1e9f : l;
    }
    #pragma unroll
    for (int off = 1; off < 64; off <<= 1) msum += __shfl_xor(msum, off, 64);
    if (lane == 0) sMsum[wv] = msum;
    float lm = fmaxf(fmaxf(lg[0], lg[1]), fmaxf(lg[2], lg[3]));
    #pragma unroll
    for (int off = 1; off < 64; off <<= 1) lm = fmaxf(lm, __shfl_xor(lm, off, 64));
    if (lane == 0) sredA[wv] = lm;
    __syncthreads();
    float gmax = fmaxf(fmaxf(sredA[0], sredA[1]), fmaxf(sredA[2], sredA[3]));
    float mtot = sMsum[0] + sMsum[1] + sMsum[2] + sMsum[3];
    float es = 0.f;
    #pragma unroll
    for (int i = 0; i < 4; i++) { e[i] = __expf(lg[i] - gmax); es += e[i]; }
    #pragma unroll
    for (int off = 1; off < 64; off <<= 1) es += __shfl_xor(es, off, 64);
    if (lane == 0) sredB[wv] = es;
    #pragma unroll
    for (int j = 0; j < 64; j++) {
        float p = pacc[j];
        #pragma unroll
        for (int off = 1; off < 64; off <<= 1) p += __shfl_xor(p, off, 64);
        if (lane == 0) sPool[wv][j] = p;
    }
    __syncthreads();
    float inv_etot = 1.f / (sredB[0] + sredB[1] + sredB[2] + sredB[3]);
    #pragma unroll
    for (int i = 0; i < 4; i++) asp[base + i*256 + tid] = e[i] * inv_etot;
    if (tid < 64)
        sPoolF[tid] = (sPool[0][tid] + sPool[1][tid] + sPool[2][tid] + sPool[3][tid]) / mtot;
    __syncthreads();
    if (tid < 128) {
        float z = bl2[tid];
        #pragma unroll 8
        for (int j = 0; j < 64; j++) z = fmaf(sPoolF[j], Wl2[j*128 + tid], z);
        ach[(size_t)bh*HD_ + tid] = 1.f / (1.f + __expf(-z));
    }
}

// ---------------------------------------------------------------------------
// Final: out = v1 * v2o * a_ch   (all (B, H*HD) flat)
// ---------------------------------------------------------------------------
__global__ void final_mul(const float* __restrict__ v1, const float* __restrict__ v2o,
                          const float* __restrict__ ach, float* __restrict__ out) {
    int i = blockIdx.x*256 + threadIdx.x;
    out[i] = v1[i] * v2o[i] * ach[i];
}

// ---------------------------------------------------------------------------
extern "C" void kernel_launch(void* const* d_in, const int* in_sizes, int n_in,
                              void* d_out, int out_size, void* d_ws, size_t ws_size,
                              hipStream_t stream) {
    (void)in_sizes; (void)n_in; (void)out_size; (void)ws_size;
    const float* query  = (const float*)d_in[0];
    const float* key    = (const float*)d_in[1];
    const float* mask   = (const float*)d_in[2];
    const float* value1 = (const float*)d_in[3];
    const float* value2 = (const float*)d_in[4];
    const float* W_q = (const float*)d_in[5];  const float* b_q = (const float*)d_in[6];
    const float* g_q = (const float*)d_in[7];  const float* beta_q = (const float*)d_in[8];
    const float* W_k = (const float*)d_in[9];  const float* b_k = (const float*)d_in[10];
    const float* g_k = (const float*)d_in[11]; const float* beta_k = (const float*)d_in[12];
    const float* W_v1 = (const float*)d_in[13]; const float* b_v1 = (const float*)d_in[14];
    const float* g_v1 = (const float*)d_in[15]; const float* beta_v1 = (const float*)d_in[16];
    const float* W_v2 = (const float*)d_in[17]; const float* b_v2 = (const float*)d_in[18];
    const float* g_v2 = (const float*)d_in[19]; const float* beta_v2 = (const float*)d_in[20];
    const float* W1  = (const float*)d_in[21]; const float* b1  = (const float*)d_in[22];
    const float* Wl  = (const float*)d_in[23]; const float* bl  = (const float*)d_in[24];
    const float* Wl2 = (const float*)d_in[25]; const float* bl2 = (const float*)d_in[26];

    char* p = (char*)d_ws;
    auto alloc = [&](size_t bytes) { char* r = p; p += (bytes + 255) & ~(size_t)255; return r; };
    __bf16* WkT   = (__bf16*)alloc((size_t)D_*D_*sizeof(__bf16));
    __bf16* Wv2T  = (__bf16*)alloc((size_t)D_*D_*sizeof(__bf16));
    float* qbuf   = (float*)alloc((size_t)B_*D_*4);
    float* v1buf  = (float*)alloc((size_t)B_*D_*4);
    float* qnb    = (float*)alloc((size_t)B_*H_*4);
    float* qw1b   = (float*)alloc((size_t)B_*H_*64*4);
    float* dotb   = (float*)alloc((size_t)B_*H_*M_*4);
    float* knb    = (float*)alloc((size_t)B_*H_*M_*4);
    float* aspb   = (float*)alloc((size_t)B_*H_*M_*4);
    float* achb   = (float*)alloc((size_t)B_*D_*4);
    float* v2ob   = (float*)alloc((size_t)B_*D_*4);

    hipMemsetAsync(v2ob, 0, (size_t)B_*D_*4, stream);
    transpose_convert<<<2048, 256, 0, stream>>>(W_k, W_v2, WkT, Wv2T);
    proj_small<<<B_*H_, 128, 0, stream>>>(query, W_q, b_q, g_q, beta_q, qbuf, qnb, W1, qw1b, 1);
    proj_small<<<B_*H_, 128, 0, stream>>>(value1, W_v1, b_v1, g_v1, beta_v1, v1buf, nullptr, nullptr, nullptr, 0);
    gemm_key<<<(BM_/TM)*(D_/HD_), 256, 0, stream>>>(key, WkT, b_k, g_k, beta_k, qbuf, dotb, knb);
    attn_small<<<B_*H_, 256, 0, stream>>>(dotb, knb, qnb, qw1b, b1, Wl, bl, Wl2, bl2, mask, aspb, achb);
    gemm_v2<<<(BM_/TM)*(D_/HD_), 256, 0, stream>>>(value2, Wv2T, b_v2, g_v2, beta_v2, aspb, v2ob);
    final_mul<<<(B_*D_)/256, 256, 0, stream>>>(v1buf, v2ob, achb, (float*)d_out);
}

// Round 2
// 1095.995 us; speedup vs baseline: 1.0502x; 1.0502x over previous
//
#include <hip/hip_runtime.h>
#include <hip/hip_bf16.h>

#define B_  64
#define M_  1024
#define D_  1024
#define H_  8
#define HD_ 128
#define BM_ (B_*M_)
#define NRT_ (BM_/128)   // 512 row tiles

#define CELU_A  1.3f
#define CELU_IA 0.7692307692307693f
#define GN_EPSF 1e-5f

typedef float floatx4 __attribute__((ext_vector_type(4)));
typedef __bf16 bf16x8 __attribute__((ext_vector_type(8)));

__device__ __forceinline__ void gload_lds16(const void* g, void* l) {
    __builtin_amdgcn_global_load_lds((const __attribute__((address_space(1))) void*)g,
                                     (__attribute__((address_space(3))) void*)l, 16, 0, 0);
}

__device__ __forceinline__ float celu_f(float x) {
    return x > 0.f ? x : (CELU_A * __expf(x * CELU_IA) - CELU_A);
}

// fragment-linear position of element (r=row-in-128-tile, c=k-in-32-tile):
// chunk = (r>>6)*256 + ((r>>4)&3)*64 + (c>>3)*16 + (r&15), elem = chunk*8 + (c&7)
__device__ __forceinline__ int frag_pos(int r, int c) {
    return (((r >> 6) * 256 + ((r >> 4) & 3) * 64 + (c >> 3) * 16 + (r & 15)) << 3) + (c & 7);
}

// ---------------------------------------------------------------------------
// prep_W: W (fp32 [k][n]) -> fragment-linear bf16 tiles.
// Tile (mtx, h, t): 128 cols of head h x 32 k's, 4096 elems, stored at
// out[((mtx*8+h)*32 + t)*4096]. grid = 512 blocks, 256 thr.
// ---------------------------------------------------------------------------
__global__ void prep_W(const float* __restrict__ Wk, const float* __restrict__ Wv2,
                       __bf16* __restrict__ out) {
    __shared__ __attribute__((aligned(16))) __bf16 sT[4096];
    const int id = blockIdx.x;
    const float* W = (id < 256) ? Wk : Wv2;
    const int ht = id & 255;
    const int h = ht >> 5, t = ht & 31;
    const int tid = threadIdx.x;
    #pragma unroll
    for (int it = 0; it < 4; it++) {
        int fid = it * 256 + tid;
        int kl = fid >> 5;            // k within tile (0..31)
        int c4 = fid & 31;            // col group (4 floats)
        floatx4 v = *(const floatx4*)(W + (size_t)(t * 32 + kl) * D_ + h * HD_ + c4 * 4);
        #pragma unroll
        for (int e = 0; e < 4; e++) {
            int c = c4 * 4 + e;       // output col within head = fragment "row"
            sT[frag_pos(c, kl)] = (__bf16)v[e];
        }
    }
    __syncthreads();
    __bf16* o = out + (size_t)id * 4096;
    *(bf16x8*)(o + tid * 8)        = *(const bf16x8*)(sT + tid * 8);
    *(bf16x8*)(o + 2048 + tid * 8) = *(const bf16x8*)(sT + 2048 + tid * 8);
}

// ---------------------------------------------------------------------------
// prep_A: rows [rt0*128 ...) of src (fp32 [BM][D]) -> fragment-linear bf16
// tiles: out[(rtL*32 + t)*4096]. grid = nrt blocks, 256 thr.
// ---------------------------------------------------------------------------
__global__ void prep_A(const float* __restrict__ src, __bf16* __restrict__ out, int rt0) {
    __shared__ __attribute__((aligned(16))) __bf16 sT[4096];
    const int rtL = blockIdx.x;
    const int rt = rt0 + rtL;
    const int tid = threadIdx.x;
    for (int t = 0; t < 32; t++) {
        #pragma unroll
        for (int it = 0; it < 4; it++) {
            int fid = it * 256 + tid;
            int r = fid >> 3;         // row in tile (0..127)
            int c4 = fid & 7;         // k group (4 floats)
            floatx4 v = *(const floatx4*)(src + (size_t)(rt * 128 + r) * D_ + t * 32 + c4 * 4);
            #pragma unroll
            for (int e = 0; e < 4; e++) sT[frag_pos(r, c4 * 4 + e)] = (__bf16)v[e];
        }
        __syncthreads();
        __bf16* o = out + (size_t)(rtL * 32 + t) * 4096;
        *(bf16x8*)(o + tid * 8)        = *(const bf16x8*)(sT + tid * 8);
        *(bf16x8*)(o + 2048 + tid * 8) = *(const bf16x8*)(sT + 2048 + tid * 8);
        __syncthreads();
    }
}

// ---------------------------------------------------------------------------
// GEMM core: 128x128 tile, bf16 MFMA 16x16x32, BK=32, pure global_load_lds
// staging from fragment-linear tiles, conflict-free LDS reads.
// grid = nrt*8 ; XCD swizzle: same row tile's 8 heads -> same XCD.
// ---------------------------------------------------------------------------
#define GEMM_CORE2(ATp, BTp)                                                            \
    const int tid = threadIdx.x;                                                        \
    const int n = blockIdx.x;                                                           \
    const int rtL = ((n >> 6) << 3) | (n & 7);                                          \
    const int h = (n >> 3) & 7;                                                         \
    const int rt = rt0 + rtL;                                                           \
    const int b = rt >> 3;                                                              \
    const int col0 = h * HD_;                                                           \
    const int lane = tid & 63;                                                          \
    const int wv = tid >> 6;                                                            \
    const int wrow = wv >> 1, wcol = wv & 1;                                            \
    const int quad = lane >> 4, l15 = lane & 15;                                        \
    floatx4 acc[4][4];                                                                  \
    {   floatx4 z = {0.f, 0.f, 0.f, 0.f};                                               \
        _Pragma("unroll") for (int i = 0; i < 4; i++)                                   \
        _Pragma("unroll") for (int j = 0; j < 4; j++) acc[i][j] = z;  }                 \
    const __bf16* Ab = ATp + (size_t)rtL * 32 * 4096 + tid * 8;                         \
    const __bf16* Bb = BTp + (size_t)h * 32 * 4096 + tid * 8;                           \
    for (int t = 0; t < 32; t++) {                                                      \
        __syncthreads();                                                                \
        gload_lds16(Ab + t * 4096,        As + tid * 8);                                \
        gload_lds16(Ab + t * 4096 + 2048, As + 2048 + tid * 8);                         \
        gload_lds16(Bb + t * 4096,        Bs + tid * 8);                                \
        gload_lds16(Bb + t * 4096 + 2048, Bs + 2048 + tid * 8);                         \
        __syncthreads();                                                                \
        bf16x8 fa[4], fb[4];                                                            \
        _Pragma("unroll") for (int i = 0; i < 4; i++)                                   \
            fa[i] = *(const bf16x8*)(As + wrow * 2048 + i * 512 + lane * 8);            \
        _Pragma("unroll") for (int i = 0; i < 4; i++)                                   \
            fb[i] = *(const bf16x8*)(Bs + wcol * 2048 + i * 512 + lane * 8);            \
        _Pragma("unroll") for (int mi = 0; mi < 4; mi++)                                \
        _Pragma("unroll") for (int ni = 0; ni < 4; ni++)                                \
            acc[mi][ni] = __builtin_amdgcn_mfma_f32_16x16x32_bf16(fa[mi], fb[ni],       \
                                                                  acc[mi][ni], 0, 0, 0);\
    }

// Key path: epilogue computes dot(q, k_row) and ||k_row|| per row.
__global__ __launch_bounds__(256, 3) void gemm_key(
    const __bf16* __restrict__ AT, const __bf16* __restrict__ BT,
    const float* __restrict__ bias, const float* __restrict__ gv,
    const float* __restrict__ betav, const float* __restrict__ qv,
    float* __restrict__ dotv, float* __restrict__ knv, int rt0) {
    __shared__ __attribute__((aligned(16))) __bf16 As[4096];
    __shared__ __attribute__((aligned(16))) __bf16 Bs[4096];
    __shared__ float red0[2][128], red1[2][128], redD[2][128], redK[2][128];

    GEMM_CORE2(AT, BT)

    float biasc[4], gc[4], bc[4], qc[4];
    #pragma unroll
    for (int ni = 0; ni < 4; ni++) {
        int c = col0 + wcol*64 + ni*16 + l15;
        biasc[ni] = bias[c]; gc[ni] = gv[c]; bc[ni] = betav[c];
        qc[ni] = qv[(size_t)b*D_ + c];
    }
    #pragma unroll
    for (int mi = 0; mi < 4; mi++)
    #pragma unroll
    for (int ni = 0; ni < 4; ni++)
    #pragma unroll
    for (int r = 0; r < 4; r++)
        acc[mi][ni][r] = celu_f(acc[mi][ni][r] + biasc[ni]);

    #pragma unroll
    for (int mi = 0; mi < 4; mi++)
    #pragma unroll
    for (int r = 0; r < 4; r++) {
        float s1 = 0.f, s2 = 0.f;
        #pragma unroll
        for (int ni = 0; ni < 4; ni++) { float v = acc[mi][ni][r]; s1 += v; s2 += v*v; }
        #pragma unroll
        for (int off = 1; off < 16; off <<= 1) { s1 += __shfl_xor(s1, off, 16); s2 += __shfl_xor(s2, off, 16); }
        if (l15 == 0) { int rr = wrow*64 + mi*16 + quad*4 + r; red0[wcol][rr] = s1; red1[wcol][rr] = s2; }
    }
    __syncthreads();
    #pragma unroll
    for (int mi = 0; mi < 4; mi++)
    #pragma unroll
    for (int r = 0; r < 4; r++) {
        int rr = wrow*64 + mi*16 + quad*4 + r;
        float s1 = red0[0][rr] + red0[1][rr];
        float s2 = red1[0][rr] + red1[1][rr];
        float mu = s1 * (1.f/HD_);
        float var = fmaxf(s2 * (1.f/HD_) - mu*mu, 0.f);
        float rstd = rsqrtf(var + GN_EPSF);
        float dp = 0.f, kp = 0.f;
        #pragma unroll
        for (int ni = 0; ni < 4; ni++) {
            float kk = (acc[mi][ni][r] - mu) * rstd * gc[ni] + bc[ni];
            dp = fmaf(kk, qc[ni], dp);
            kp = fmaf(kk, kk, kp);
        }
        #pragma unroll
        for (int off = 1; off < 16; off <<= 1) { dp += __shfl_xor(dp, off, 16); kp += __shfl_xor(kp, off, 16); }
        if (l15 == 0) { redD[wcol][rr] = dp; redK[wcol][rr] = kp; }
    }
    __syncthreads();
    if (tid < 128) {
        int gr = rt * 128 + tid;
        size_t oi = ((size_t)(b*H_ + h)) * M_ + (gr & (M_ - 1));
        dotv[oi] = redD[0][tid] + redD[1][tid];
        knv[oi]  = sqrtf(redK[0][tid] + redK[1][tid]);
    }
}

// value2 path: epilogue accumulates v2o[b,h,:] += a_sp[b,h,m] * v2_row
__global__ __launch_bounds__(256, 3) void gemm_v2(
    const __bf16* __restrict__ AT, const __bf16* __restrict__ BT,
    const float* __restrict__ bias, const float* __restrict__ gv,
    const float* __restrict__ betav, const float* __restrict__ asp,
    float* __restrict__ v2o, int rt0) {
    __shared__ __attribute__((aligned(16))) __bf16 As[4096];
    __shared__ __attribute__((aligned(16))) __bf16 Bs[4096];
    __shared__ float red0[2][128], red1[2][128];
    __shared__ float sAsp[128];

    GEMM_CORE2(AT, BT)

    if (tid < 128) {
        int gr = rt * 128 + tid;
        sAsp[tid] = asp[((size_t)(b*H_ + h)) * M_ + (gr & (M_ - 1))];
    }
    float biasc[4], gc[4], bc[4];
    #pragma unroll
    for (int ni = 0; ni < 4; ni++) {
        int c = col0 + wcol*64 + ni*16 + l15;
        biasc[ni] = bias[c]; gc[ni] = gv[c]; bc[ni] = betav[c];
    }
    #pragma unroll
    for (int mi = 0; mi < 4; mi++)
    #pragma unroll
    for (int ni = 0; ni < 4; ni++)
    #pragma unroll
    for (int r = 0; r < 4; r++)
        acc[mi][ni][r] = celu_f(acc[mi][ni][r] + biasc[ni]);

    #pragma unroll
    for (int mi = 0; mi < 4; mi++)
    #pragma unroll
    for (int r = 0; r < 4; r++) {
        float s1 = 0.f, s2 = 0.f;
        #pragma unroll
        for (int ni = 0; ni < 4; ni++) { float v = acc[mi][ni][r]; s1 += v; s2 += v*v; }
        #pragma unroll
        for (int off = 1; off < 16; off <<= 1) { s1 += __shfl_xor(s1, off, 16); s2 += __shfl_xor(s2, off, 16); }
        if (l15 == 0) { int rr = wrow*64 + mi*16 + quad*4 + r; red0[wcol][rr] = s1; red1[wcol][rr] = s2; }
    }
    __syncthreads();
    float cs[4] = {0.f, 0.f, 0.f, 0.f};
    #pragma unroll
    for (int mi = 0; mi < 4; mi++)
    #pragma unroll
    for (int r = 0; r < 4; r++) {
        int rr = wrow*64 + mi*16 + quad*4 + r;
        float s1 = red0[0][rr] + red0[1][rr];
        float s2 = red1[0][rr] + red1[1][rr];
        float mu = s1 * (1.f/HD_);
        float var = fmaxf(s2 * (1.f/HD_) - mu*mu, 0.f);
        float rstd = rsqrtf(var + GN_EPSF);
        float w = sAsp[rr];
        #pragma unroll
        for (int ni = 0; ni < 4; ni++) {
            float vv = (acc[mi][ni][r] - mu) * rstd * gc[ni] + bc[ni];
            cs[ni] = fmaf(w, vv, cs[ni]);
        }
    }
    #pragma unroll
    for (int ni = 0; ni < 4; ni++) {
        cs[ni] += __shfl_xor(cs[ni], 16, 64);
        cs[ni] += __shfl_xor(cs[ni], 32, 64);
    }
    if (quad == 0) {
        #pragma unroll
        for (int ni = 0; ni < 4; ni++)
            atomicAdd(&v2o[(size_t)b*D_ + col0 + wcol*64 + ni*16 + l15], cs[ni]);
    }
}

// ---------------------------------------------------------------------------
// Small projection (query / value1) — unchanged from round 1.
// ---------------------------------------------------------------------------
__global__ void proj_small(const float* __restrict__ x, const float* __restrict__ W,
                           const float* __restrict__ bias, const float* __restrict__ g,
                           const float* __restrict__ beta, float* __restrict__ out,
                           float* __restrict__ qn_out, const float* __restrict__ W1,
                           float* __restrict__ qw1, int extras) {
    __shared__ float sX[D_];
    __shared__ float sred[4];
    __shared__ float sQd[HD_];
    const int bh = blockIdx.x;
    const int b = bh >> 3, h = bh & 7;
    const int tid = threadIdx.x;  // 128

    #pragma unroll
    for (int i = 0; i < D_/128; i++) sX[i*128 + tid] = x[(size_t)b*D_ + i*128 + tid];
    __syncthreads();

    const int col = h*HD_ + tid;
    float acc = bias[col];
    const float* Wp = W + col;
    #pragma unroll 16
    for (int d = 0; d < D_; d++) acc = fmaf(sX[d], Wp[(size_t)d*D_], acc);

    float y = celu_f(acc);

    float s1 = y, s2 = y*y;
    #pragma unroll
    for (int off = 1; off < 64; off <<= 1) { s1 += __shfl_xor(s1, off, 64); s2 += __shfl_xor(s2, off, 64); }
    if ((tid & 63) == 0) { sred[tid >> 6] = s1; sred[2 + (tid >> 6)] = s2; }
    __syncthreads();
    s1 = sred[0] + sred[1]; s2 = sred[2] + sred[3];
    float mu = s1 * (1.f/HD_);
    float var = fmaxf(s2 * (1.f/HD_) - mu*mu, 0.f);
    float rstd = rsqrtf(var + GN_EPSF);
    float k = (y - mu) * rstd * g[col] + beta[col];
    out[(size_t)b*D_ + col] = k;

    if (extras) {
        __syncthreads();
        float q2 = k*k;
        #pragma unroll
        for (int off = 1; off < 64; off <<= 1) q2 += __shfl_xor(q2, off, 64);
        if ((tid & 63) == 0) sred[tid >> 6] = q2;
        __syncthreads();
        float qn = sqrtf(sred[0] + sred[1]);
        if (tid == 0) qn_out[bh] = qn;
        sQd[tid] = k / fmaxf(qn, 1e-12f);
        __syncthreads();
        if (tid < 64) {
            float s = 0.f;
            #pragma unroll 16
            for (int d2 = 0; d2 < HD_; d2++) s = fmaf(sQd[d2], W1[d2*64 + tid], s);
            qw1[bh*64 + tid] = s;
        }
    }
}

// ---------------------------------------------------------------------------
// attn_small — unchanged from round 1.
// ---------------------------------------------------------------------------
__global__ __launch_bounds__(256) void attn_small(
    const float* __restrict__ dotv, const float* __restrict__ knv,
    const float* __restrict__ qn_in, const float* __restrict__ qw1,
    const float* __restrict__ b1, const float* __restrict__ Wl,
    const float* __restrict__ bl, const float* __restrict__ Wl2,
    const float* __restrict__ bl2, const float* __restrict__ mask,
    float* __restrict__ asp, float* __restrict__ ach) {
    __shared__ float sqw[64], sb1[64], sWl[64];
    __shared__ float sredA[4], sredB[4], sMsum[4];
    __shared__ float sPool[4][64];
    __shared__ float sPoolF[64];
    const int bh = blockIdx.x;
    const int b = bh >> 3;
    const int tid = threadIdx.x, lane = tid & 63, wv = tid >> 6;
    if (tid < 64) { sqw[tid] = qw1[bh*64 + tid]; sb1[tid] = b1[tid]; sWl[tid] = Wl[tid]; }
    __syncthreads();
    const float rqn = 1.f / fmaxf(qn_in[bh], 1e-8f);
    const float blv = bl[0];
    const size_t base = (size_t)bh * M_;
    float pacc[64];
    #pragma unroll
    for (int j = 0; j < 64; j++) pacc[j] = 0.f;
    float lg[4], e[4];
    float msum = 0.f;
    #pragma unroll
    for (int i = 0; i < 4; i++) {
        int m = i*256 + tid;
        float kn = fmaxf(knv[base + m], 1e-8f);
        float cosv = dotv[base + m] * rqn / kn;
        float mk = mask[(size_t)b*M_ + m];
        msum += mk;
        float l = blv;
        #pragma unroll
        for (int j = 0; j < 64; j++) {
            float a = fmaxf(fmaf(cosv, sqw[j], sb1[j]), 0.f);
            l = fmaf(a, sWl[j], l);
            pacc[j] = fmaf(a, mk, pacc[j]);
        }
        lg[i] = (mk == 0.f) ? -1e9f : l;
    }
    #pragma unroll
    for (int off = 1; off < 64; off <<= 1) msum += __shfl_xor(msum, off, 64);
    if (lane == 0) sMsum[wv] = msum;
    float lm = fmaxf(fmaxf(lg[0], lg[1]), fmaxf(lg[2], lg[3]));
    #pragma unroll
    for (int off = 1; off < 64; off <<= 1) lm = fmaxf(lm, __shfl_xor(lm, off, 64));
    if (lane == 0) sredA[wv] = lm;
    __syncthreads();
    float gmax = fmaxf(fmaxf(sredA[0], sredA[1]), fmaxf(sredA[2], sredA[3]));
    float mtot = sMsum[0] + sMsum[1] + sMsum[2] + sMsum[3];
    float es = 0.f;
    #pragma unroll
    for (int i = 0; i < 4; i++) { e[i] = __expf(lg[i] - gmax); es += e[i]; }
    #pragma unroll
    for (int off = 1; off < 64; off <<= 1) es += __shfl_xor(es, off, 64);
    if (lane == 0) sredB[wv] = es;
    #pragma unroll
    for (int j = 0; j < 64; j++) {
        float p = pacc[j];
        #pragma unroll
        for (int off = 1; off < 64; off <<= 1) p += __shfl_xor(p, off, 64);
        if (lane == 0) sPool[wv][j] = p;
    }
    __syncthreads();
    float inv_etot = 1.f / (sredB[0] + sredB[1] + sredB[2] + sredB[3]);
    #pragma unroll
    for (int i = 0; i < 4; i++) asp[base + i*256 + tid] = e[i] * inv_etot;
    if (tid < 64)
        sPoolF[tid] = (sPool[0][tid] + sPool[1][tid] + sPool[2][tid] + sPool[3][tid]) / mtot;
    __syncthreads();
    if (tid < 128) {
        float z = bl2[tid];
        #pragma unroll 8
        for (int j = 0; j < 64; j++) z = fmaf(sPoolF[j], Wl2[j*128 + tid], z);
        ach[(size_t)bh*HD_ + tid] = 1.f / (1.f + __expf(-z));
    }
}

__global__ void final_mul(const float* __restrict__ v1, const float* __restrict__ v2o,
                          const float* __restrict__ ach, float* __restrict__ out) {
    int i = blockIdx.x*256 + threadIdx.x;
    out[i] = v1[i] * v2o[i] * ach[i];
}

// ---------------------------------------------------------------------------
extern "C" void kernel_launch(void* const* d_in, const int* in_sizes, int n_in,
                              void* d_out, int out_size, void* d_ws, size_t ws_size,
                              hipStream_t stream) {
    (void)in_sizes; (void)n_in; (void)out_size;
    const float* query  = (const float*)d_in[0];
    const float* key    = (const float*)d_in[1];
    const float* mask   = (const float*)d_in[2];
    const float* value1 = (const float*)d_in[3];
    const float* value2 = (const float*)d_in[4];
    const float* W_q = (const float*)d_in[5];  const float* b_q = (const float*)d_in[6];
    const float* g_q = (const float*)d_in[7];  const float* beta_q = (const float*)d_in[8];
    const float* W_k = (const float*)d_in[9];  const float* b_k = (const float*)d_in[10];
    const float* g_k = (const float*)d_in[11]; const float* beta_k = (const float*)d_in[12];
    const float* W_v1 = (const float*)d_in[13]; const float* b_v1 = (const float*)d_in[14];
    const float* g_v1 = (const float*)d_in[15]; const float* beta_v1 = (const float*)d_in[16];
    const float* W_v2 = (const float*)d_in[17]; const float* b_v2 = (const float*)d_in[18];
    const float* g_v2 = (const float*)d_in[19]; const float* beta_v2 = (const float*)d_in[20];
    const float* W1  = (const float*)d_in[21]; const float* b1  = (const float*)d_in[22];
    const float* Wl  = (const float*)d_in[23]; const float* bl  = (const float*)d_in[24];
    const float* Wl2 = (const float*)d_in[25]; const float* bl2 = (const float*)d_in[26];

    char* p = (char*)d_ws;
    auto alloc = [&](size_t bytes) { char* r = p; p += (bytes + 255) & ~(size_t)255; return r; };
    __bf16* Wtiles = (__bf16*)alloc((size_t)2*D_*D_*sizeof(__bf16));  // 4 MB
    float* qbuf   = (float*)alloc((size_t)B_*D_*4);
    float* v1buf  = (float*)alloc((size_t)B_*D_*4);
    float* qnb    = (float*)alloc((size_t)B_*H_*4);
    float* qw1b   = (float*)alloc((size_t)B_*H_*64*4);
    float* dotb   = (float*)alloc((size_t)B_*H_*M_*4);
    float* knb    = (float*)alloc((size_t)B_*H_*M_*4);
    float* aspb   = (float*)alloc((size_t)B_*H_*M_*4);
    float* achb   = (float*)alloc((size_t)B_*D_*4);
    float* v2ob   = (float*)alloc((size_t)B_*D_*4);

    // A-tile chunk buffer: as big as workspace allows (power-of-2 row tiles)
    size_t used = (size_t)(p - (char*)d_ws);
    int nrtc = NRT_;
    while (nrtc > 8 && used + (size_t)nrtc * 32 * 4096 * sizeof(__bf16) > ws_size) nrtc >>= 1;
    __bf16* Atiles = (__bf16*)alloc((size_t)nrtc * 32 * 4096 * sizeof(__bf16));

    const __bf16* WTk  = Wtiles;              // tiles for W_k
    const __bf16* WTv2 = Wtiles + (size_t)D_*D_;  // tiles for W_v2

    hipMemsetAsync(v2ob, 0, (size_t)B_*D_*4, stream);
    prep_W<<<512, 256, 0, stream>>>(W_k, W_v2, Wtiles);
    proj_small<<<B_*H_, 128, 0, stream>>>(query, W_q, b_q, g_q, beta_q, qbuf, qnb, W1, qw1b, 1);
    proj_small<<<B_*H_, 128, 0, stream>>>(value1, W_v1, b_v1, g_v1, beta_v1, v1buf, nullptr, nullptr, nullptr, 0);

    for (int rt0 = 0; rt0 < NRT_; rt0 += nrtc) {
        prep_A<<<nrtc, 256, 0, stream>>>(key, Atiles, rt0);
        gemm_key<<<nrtc*8, 256, 0, stream>>>(Atiles, WTk, b_k, g_k, beta_k, qbuf, dotb, knb, rt0);
    }
    attn_small<<<B_*H_, 256, 0, stream>>>(dotb, knb, qnb, qw1b, b1, Wl, bl, Wl2, bl2, mask, aspb, achb);
    for (int rt0 = 0; rt0 < NRT_; rt0 += nrtc) {
        prep_A<<<nrtc, 256, 0, stream>>>(value2, Atiles, rt0);
        gemm_v2<<<nrtc*8, 256, 0, stream>>>(Atiles, WTv2, b_v2, g_v2, beta_v2, aspb, v2ob, rt0);
    }
    final_mul<<<(B_*D_)/256, 256, 0, stream>>>(v1buf, v2ob, achb, (float*)d_out);
}